// Round 9
// baseline (136.849 us; speedup 1.0000x reference)
//
#include <hip/hip_runtime.h>

// B=64, C=1024, HW=1024. x fp32 [B,C,HW] = 256 MiB.
// ONE-read, NO-sync design. Block = (b, 64-hw tile); 512 threads hold the
// whole x[b, :, hw0:hw0+64] tile (256 KB) in REGISTERS (32 float4/thread).
//   thread t: col-group g = t&15 (cols 4g..4g+3), row-part rp = t>>4;
//   iter i loads row i*32+rp -> per wave-instr: 4 rows x 256B contiguous
//   fully-consumed segments; the 16 co-resident sibling tiles of batch b
//   cover complementary 256B columns of the SAME 4KB rows -> DRAM sees
//   full-row sequential traffic (fixes R2's 16B/line and R3's 64B granules).
// scores accumulate fp32 during staging (exact); local tile softmax
// (m_t, Z_t); partial pool from registers; combine kernel rescales
// (R2/R3-verified flash-softmax math). Zero atomics/spins (R5-R7 lesson).
// Traffic: 256 MiB + 8 MiB partials ~= 42 us floor.
#define NB 64
#define NC 1024
#define NHW 1024
#define THW 64               // hw per tile
#define NT (NHW / THW)       // 16 tiles per batch

// grid = NB*NT = 1024 blocks; 4 blocks/CU (32 waves) -> whole grid resident.
__global__ __launch_bounds__(512, 8) void tile_kernel(
        const float* __restrict__ x, const float* __restrict__ w,
        float* __restrict__ partial, float* __restrict__ mz) {
    __shared__ float w_lds[NC];          // 4 KB
    __shared__ float scr[8][THW];        // 2 KB per-wave score partials
    __shared__ float e_lds[THW];         // 256 B
    __shared__ float pool_lds[NC];       // 4 KB

    const int tid  = threadIdx.x;
    const int lane = tid & 63;
    const int wv   = tid >> 6;           // wave 0..7
    const int g    = tid & 15;           // col group: cols 4g..4g+3
    const int rp   = tid >> 4;           // row part 0..31
    const int bid  = blockIdx.x;
    const int b    = bid >> 4;
    const int hw0  = (bid & 15) * THW;

    if (tid < NC / 4)
        reinterpret_cast<float4*>(w_lds)[tid] =
            reinterpret_cast<const float4*>(w)[tid];
    __syncthreads();

    // ---- stage tile into registers + accumulate partial scores (fp32) ----
    const float* xb = x + ((size_t)b * NC) * NHW + hw0 + g * 4;
    float4 v[32];
    float sp[4] = {0.f, 0.f, 0.f, 0.f};
    #pragma unroll
    for (int i = 0; i < 32; ++i) {
        const int row = i * 32 + rp;
        v[i] = *reinterpret_cast<const float4*>(xb + (size_t)row * NHW);
        const float wr = w_lds[row];     // 4 distinct banks/wave, broadcast
        sp[0] += v[i].x * wr;  sp[1] += v[i].y * wr;
        sp[2] += v[i].z * wr;  sp[3] += v[i].w * wr;
    }
    // sum over rp within wave (lanes +16,+32 share g)
    #pragma unroll
    for (int k = 0; k < 4; ++k) {
        sp[k] += __shfl_xor(sp[k], 16);
        sp[k] += __shfl_xor(sp[k], 32);
    }
    if (lane < 16)                       // lane == g
        *reinterpret_cast<float4*>(&scr[wv][lane * 4]) =
            make_float4(sp[0], sp[1], sp[2], sp[3]);
    __syncthreads();

    // ---- local softmax over the 64 tile scores (wave 0) ----
    // bias dropped: softmax shift-invariance.
    if (tid < THW) {
        float s = 0.f;
        #pragma unroll
        for (int k = 0; k < 8; ++k) s += scr[k][tid];
        float m = s;
        #pragma unroll
        for (int off = 32; off; off >>= 1) m = fmaxf(m, __shfl_xor(m, off));
        float e = __expf(s - m);
        float z = e;
        #pragma unroll
        for (int off = 32; off; off >>= 1) z += __shfl_xor(z, off);
        e_lds[tid] = e;
        if (tid == 0) { mz[2 * bid] = m; mz[2 * bid + 1] = z; }
    }
    __syncthreads();

    // ---- partial pool from registers: p[row] = sum_col v[row,col]*e[col] ----
    const float4 ev = *reinterpret_cast<const float4*>(&e_lds[g * 4]);
    #pragma unroll
    for (int i = 0; i < 32; ++i) {
        float t = v[i].x * ev.x + v[i].y * ev.y + v[i].z * ev.z + v[i].w * ev.w;
        t += __shfl_xor(t, 1);           // sum the 16 col-groups
        t += __shfl_xor(t, 2);
        t += __shfl_xor(t, 4);
        t += __shfl_xor(t, 8);
        if (g == 0) pool_lds[i * 32 + rp] = t;
    }
    __syncthreads();

    // coalesced partial store: 512 threads x float2 = 4 KB
    reinterpret_cast<float2*>(partial + (size_t)bid * NC)[tid] =
        reinterpret_cast<const float2*>(pool_lds)[tid];
}

// out[b,c] = sum_t partial[b*NT+t][c] * exp(m_t - M_b) / Z_b
// grid = NB*4 = 256 blocks, 256 threads (thread = one c).
__global__ __launch_bounds__(256) void combine_kernel(
        const float* __restrict__ partial, const float* __restrict__ mz,
        float* __restrict__ out) {
    __shared__ float scale[NT];
    const int tid = threadIdx.x;
    const int b   = blockIdx.x >> 2;
    const int c   = ((blockIdx.x & 3) << 8) + tid;

    if (tid < NT) {                      // lanes 0..15 of wave 0
        const float m_t = mz[2 * (b * NT + tid)];
        const float z_t = mz[2 * (b * NT + tid) + 1];
        float M = m_t;
        #pragma unroll
        for (int off = 8; off; off >>= 1) M = fmaxf(M, __shfl_xor(M, off, 16));
        const float ew = __expf(m_t - M);
        float Z = z_t * ew;
        #pragma unroll
        for (int off = 8; off; off >>= 1) Z += __shfl_xor(Z, off, 16);
        scale[tid] = ew / Z;
    }
    __syncthreads();

    float acc = 0.f;
    const float* p = partial + (size_t)b * NT * NC + c;
    #pragma unroll
    for (int t = 0; t < NT; ++t)
        acc += p[(size_t)t * NC] * scale[t];
    out[b * NC + c] = acc;
}

extern "C" void kernel_launch(void* const* d_in, const int* in_sizes, int n_in,
                              void* d_out, int out_size, void* d_ws, size_t ws_size,
                              hipStream_t stream) {
    const float* x = (const float*)d_in[0];
    const float* w = (const float*)d_in[1];
    // d_in[2] (bias) irrelevant under softmax (shift-invariance).
    float* out     = (float*)d_out;
    float* partial = (float*)d_ws;                       // 1024*1024 f32 = 4 MiB
    float* mz      = partial + (size_t)NB * NT * NC;     // 2048 f32

    tile_kernel<<<NB * NT, 512, 0, stream>>>(x, w, partial, mz);
    combine_kernel<<<NB * 4, 256, 0, stream>>>(partial, mz, out);
}